// Round 6
// baseline (179.138 us; speedup 1.0000x reference)
//
#include <hip/hip_runtime.h>

#define BATCH 65536
#define IN_DIM 128
#define INT_NODES 255
#define LEAF 256
#define OUT_DIM 8
#define ROWS_PB 64
#define NBLK (BATCH / ROWS_PB)   // 1024 blocks, 4/CU -> whole grid co-resident
#define AMB_TH 5e-4f

typedef float  f4v __attribute__((ext_vector_type(4)));
typedef short  s8v __attribute__((ext_vector_type(8)));

__device__ __forceinline__ unsigned short bfhi(float f) {
    unsigned u = __builtin_bit_cast(unsigned, f);
    unsigned r = (u + 0x7FFFu + ((u >> 16) & 1u)) >> 16;   // RNE
    return (unsigned short)r;
}
__device__ __forceinline__ float bf2f(unsigned short h) {
    unsigned u = ((unsigned)h) << 16;
    return __builtin_bit_cast(float, u);
}

// Fused prepass: blocks [0,64) = LDS-tiled transpose Wor[o*128+i][l] -> Wor_t[l][o*128+i]
// (coalesced read AND write; R5's naive version was a scattered-read gather);
// blocks [64,192) = Wp -> MFMA B-fragments, bf16 hi/lo split, node 255 zero-pad.
__global__ __launch_bounds__(256) void prep(const float* __restrict__ Wor,
                                            float* __restrict__ Wor_t,
                                            const float* __restrict__ Wp,
                                            unsigned short* __restrict__ Bh,
                                            unsigned short* __restrict__ Bl) {
    if (blockIdx.x < 64) {
        __shared__ float t[64][65];
        const int rt = blockIdx.x >> 2, ct = blockIdx.x & 3;  // 16 x 4 tiles of 64x64
        const int r0 = rt * 64, c0 = ct * 64;
        const int tx = threadIdx.x & 63, ty = threadIdx.x >> 6;
#pragma unroll
        for (int p = 0; p < 16; ++p) {
            int r = ty + p * 4;
            t[r][tx] = Wor[(size_t)(r0 + r) * 256 + c0 + tx];     // coalesced
        }
        __syncthreads();
#pragma unroll
        for (int p = 0; p < 16; ++p) {
            int r = ty + p * 4;
            Wor_t[(size_t)(c0 + r) * 1024 + r0 + tx] = t[tx][r];  // coalesced
        }
    } else {
        // B-frag (16x16x32): B[k = ks*32+(lane>>4)*8+j][n = ntg*16+(lane&15)],
        // slot = ((ks*16+ntg)*64+lane)*8+j.
        int slot = (blockIdx.x - 64) * 256 + threadIdx.x;   // 32768
        int j    = slot & 7;
        int lane = (slot >> 3) & 63;
        int ntg  = (slot >> 9) & 15;
        int ks   = slot >> 13;
        int n = ntg * 16 + (lane & 15);
        int k = ks * 32 + (lane >> 4) * 8 + j;
        float v = (n < INT_NODES) ? Wp[n * IN_DIM + k] : 0.f;
        unsigned short h = bfhi(v);
        Bh[slot] = h;
        Bl[slot] = bfhi(v - bf2f(h));
    }
}

__global__ __launch_bounds__(256, 4) void dgt_main(
    const float* __restrict__ x, const float* __restrict__ Wp,
    const float* __restrict__ bp, const unsigned short* __restrict__ Bhg,
    const unsigned short* __restrict__ Blg, const float* __restrict__ Wor_t,
    const float* __restrict__ bor, const float* __restrict__ stds,
    float* __restrict__ out, float* __restrict__ stdo) {

    // ~37 KB LDS -> 4 blocks/CU (R5's 75 KB z-tile allowed only 2).
    __shared__ union {
        float ps[64 * 68];          // row-partials of sum|z+bp|: [m][wave*16+c]
        float hb[2 * 8 * 4 * 64];   // heads partials (phases 6-7; ps is dead)
    } u;
    __shared__ unsigned char sgn[256 * 72];  // 2-bit sign/ambig per (node,row)
    __shared__ float bpl[256];
    __shared__ int   leafbuf[64];
    __shared__ float psbuf[64];

    const int tid  = threadIdx.x;
    const int wave = tid >> 6;
    const int lane = tid & 63;
    const int rowbase = blockIdx.x * ROWS_PB;

    bpl[tid] = (tid < INT_NODES) ? bp[tid] : 0.f;

    // ---- phase 1+2: A-frags straight from global x (in-register, no LDS),
    //      3-product split-bf16 MFMA: z = xh*wh + xh*wl + xl*wh (fp32 acc). ----
    f4v acc[4][4];
#pragma unroll
    for (int mt = 0; mt < 4; ++mt)
#pragma unroll
        for (int nt = 0; nt < 4; ++nt) acc[mt][nt] = (f4v){0.f, 0.f, 0.f, 0.f};

    const s8v* Bh8 = (const s8v*)Bhg;
    const s8v* Bl8 = (const s8v*)Blg;
    const float* xbase = x + (size_t)rowbase * IN_DIM;
    const int arow = lane & 15, akq = lane >> 4;

#pragma unroll
    for (int ks = 0; ks < 4; ++ks) {
        s8v ah[4], al[4];
#pragma unroll
        for (int mt = 0; mt < 4; ++mt) {
            const float* p = xbase + (size_t)(mt * 16 + arow) * IN_DIM + ks * 32 + akq * 8;
            float4 v0 = *reinterpret_cast<const float4*>(p);
            float4 v1 = *reinterpret_cast<const float4*>(p + 4);
            float f[8] = {v0.x, v0.y, v0.z, v0.w, v1.x, v1.y, v1.z, v1.w};
            s8v hi, lo;
#pragma unroll
            for (int j = 0; j < 8; ++j) {
                unsigned short h = bfhi(f[j]);
                hi[j] = (short)h;
                lo[j] = (short)bfhi(f[j] - bf2f(h));
            }
            ah[mt] = hi; al[mt] = lo;
        }
#pragma unroll
        for (int nt = 0; nt < 4; ++nt) {
            int idx = (ks * 16 + (wave * 4 + nt)) * 64 + lane;   // coalesced, L2-hot
            s8v bh = Bh8[idx];
            s8v bl = Bl8[idx];
#pragma unroll
            for (int mt = 0; mt < 4; ++mt) {
                acc[mt][nt] = __builtin_amdgcn_mfma_f32_16x16x32_bf16(ah[mt], bh, acc[mt][nt], 0, 0, 0);
                acc[mt][nt] = __builtin_amdgcn_mfma_f32_16x16x32_bf16(ah[mt], bl, acc[mt][nt], 0, 0, 0);
                acc[mt][nt] = __builtin_amdgcn_mfma_f32_16x16x32_bf16(al[mt], bh, acc[mt][nt], 0, 0, 0);
            }
        }
    }
    __syncthreads();   // covers bpl write -> read

    // ---- phase 3: compress acc -> 2-bit sign/ambig bytes + in-register
    //      row-partials of sum|z+bp| (z never materialized in LDS). ----
    // C/D layout: col n = wave*64 + nt*16 + (lane&15), row m = mt*16 + (lane>>4)*4 + reg.
    {
        const int c = lane & 15, g = lane >> 4;
        float pp[4][4];
#pragma unroll
        for (int mt = 0; mt < 4; ++mt)
#pragma unroll
            for (int r = 0; r < 4; ++r) pp[mt][r] = 0.f;

#pragma unroll
        for (int nt = 0; nt < 4; ++nt) {
            const int n = wave * 64 + nt * 16 + c;
            const float bpv = bpl[n];
#pragma unroll
            for (int mt = 0; mt < 4; ++mt) {
                unsigned pk = 0;
#pragma unroll
                for (int r = 0; r < 4; ++r) {
                    float v = acc[mt][nt][r] + bpv;
                    float av = fabsf(v);
                    pp[mt][r] += av;
                    unsigned b = (v < 0.f ? 1u : 0u) | (av < AMB_TH ? 2u : 0u);
                    pk |= b << (8 * r);
                }
                *reinterpret_cast<unsigned*>(&sgn[n * 72 + mt * 16 + g * 4]) = pk;
            }
        }
#pragma unroll
        for (int mt = 0; mt < 4; ++mt)
#pragma unroll
            for (int r = 0; r < 4; ++r)
                u.ps[(mt * 16 + g * 4 + r) * 68 + wave * 16 + c] = pp[mt][r];
    }
    __syncthreads();

    // ---- phase 5: traversal + closed-form p* (wave 0; 8 byte-lookups) ----
    if (wave == 0) {
        const int r = lane;
        float s = 0.f;
#pragma unroll
        for (int j = 0; j < 64; j += 4) {
            float4 v = *reinterpret_cast<const float4*>(&u.ps[r * 68 + j]);
            s += (v.x + v.y) + (v.z + v.w);
        }
        int node = 0;
#pragma unroll
        for (int d = 0; d < 8; ++d) {
            unsigned b = sgn[node * 72 + r];
            int neg;
            if (b & 2u) {          // rare: exact sign via fp64 from global
                double zd = (double)bpl[node];
                const float* wr = Wp + node * IN_DIM;
                const float* xrow = x + (size_t)(rowbase + r) * IN_DIM;
                for (int k = 0; k < IN_DIM; ++k)
                    zd = fma((double)wr[k], (double)xrow[k], zd);
                neg = (zd < 0.0) ? 1 : 0;
            } else {
                neg = (int)(b & 1u);
            }
            node = 2 * node + 1 + neg;
        }
        const float fac = s * (1.0f / (float)INT_NODES);
        // p* of argmax leaf: sum_l exp(and_z_l - 8 fac) = (1 + e^{-2 fac})^8.
        const float e = expf(-2.0f * fac);
        const float q = 1.0f + e;
        const float q2 = q * q, q4 = q2 * q2, q8 = q4 * q4;
        leafbuf[r] = node - INT_NODES;
        psbuf[r] = 1.0f / q8;
    }
    __syncthreads();

    // ---- phase 6: fp32 heads, K-split (identical numerics to R4/R5) ----
    {
        const int r = lane, sg = wave;
        const float* xp = x + (size_t)(rowbase + r) * IN_DIM + sg * 32;
        float xr[32];
#pragma unroll
        for (int i = 0; i < 32; i += 4) {
            float4 v = *reinterpret_cast<const float4*>(xp + i);
            xr[i] = v.x; xr[i + 1] = v.y; xr[i + 2] = v.z; xr[i + 3] = v.w;
        }
        const int leaf = leafbuf[r];
        const float* wl = Wor_t + (size_t)leaf * (OUT_DIM * IN_DIM) + sg * 32;
        const float* bb = bor + sg * 32;
#pragma unroll
        for (int o = 0; o < OUT_DIM; ++o) {
            const float* wo = wl + o * IN_DIM;
            const float* bo = bb + o * IN_DIM;
            float s0 = 0.f, s1 = 0.f, s2 = 0.f, s3 = 0.f;
            float b0 = 0.f, b1 = 0.f, b2 = 0.f, b3 = 0.f;
#pragma unroll
            for (int c2 = 0; c2 < 32; c2 += 4) {
                float4 wv = *reinterpret_cast<const float4*>(wo + c2);
                s0 = fmaf(wv.x, xr[c2 + 0], s0);
                s1 = fmaf(wv.y, xr[c2 + 1], s1);
                s2 = fmaf(wv.z, xr[c2 + 2], s2);
                s3 = fmaf(wv.w, xr[c2 + 3], s3);
                b0 = fmaf(bo[c2 + 0], xr[c2 + 0], b0);
                b1 = fmaf(bo[c2 + 1], xr[c2 + 1], b1);
                b2 = fmaf(bo[c2 + 2], xr[c2 + 2], b2);
                b3 = fmaf(bo[c2 + 3], xr[c2 + 3], b3);
            }
            u.hb[((0 * 8 + o) * 4 + sg) * 64 + r] = (s0 + s1) + (s2 + s3);
            u.hb[((1 * 8 + o) * 4 + sg) * 64 + r] = (b0 + b1) + (b2 + b3);
        }
    }
    __syncthreads();

    // ---- phase 7: final reduce + stores (2 outputs/thread) ----
    {
        const int r = tid & 63;
        const int og = tid >> 6;
        const float ps = psbuf[r];
        const int lf = leafbuf[r];
#pragma unroll
        for (int uu = 0; uu < 2; ++uu) {
            const int o = og * 2 + uu;
            float s = u.hb[((0 * 8 + o) * 4 + 0) * 64 + r] + u.hb[((0 * 8 + o) * 4 + 1) * 64 + r]
                    + u.hb[((0 * 8 + o) * 4 + 2) * 64 + r] + u.hb[((0 * 8 + o) * 4 + 3) * 64 + r];
            float b = u.hb[((1 * 8 + o) * 4 + 0) * 64 + r] + u.hb[((1 * 8 + o) * 4 + 1) * 64 + r]
                    + u.hb[((1 * 8 + o) * 4 + 2) * 64 + r] + u.hb[((1 * 8 + o) * 4 + 3) * 64 + r];
            out[(size_t)(rowbase + r) * OUT_DIM + o] = ps * s + b;
            float sd = ps * stds[lf * OUT_DIM + o];
            stdo[(size_t)(rowbase + r) * OUT_DIM + o] = fminf(fmaxf(sd, -20.0f), 2.0f);
        }
    }
}

extern "C" void kernel_launch(void* const* d_in, const int* in_sizes, int n_in,
                              void* d_out, int out_size, void* d_ws, size_t ws_size,
                              hipStream_t stream) {
    const float* x    = (const float*)d_in[0];
    const float* Wp   = (const float*)d_in[1];
    const float* bp   = (const float*)d_in[2];
    // d_in[3] = Wand -- folded into the traversal, unused.
    const float* Wor  = (const float*)d_in[4];
    const float* bor  = (const float*)d_in[5];
    const float* stds = (const float*)d_in[6];
    float* out = (float*)d_out;

    float* wor_t = (float*)d_ws;                                              // 1 MB
    unsigned short* Bh = (unsigned short*)((char*)d_ws + (1 << 20));          // 64 KB
    unsigned short* Bl = (unsigned short*)((char*)d_ws + (1 << 20) + (64 << 10)); // 64 KB

    prep<<<192, 256, 0, stream>>>(Wor, wor_t, Wp, Bh, Bl);
    dgt_main<<<NBLK, 256, 0, stream>>>(x, Wp, bp, Bh, Bl, wor_t, bor, stds,
                                       out, out + (size_t)BATCH * OUT_DIM);
}

// Round 7
// 151.148 us; speedup vs baseline: 1.1852x; 1.1852x over previous
//
#include <hip/hip_runtime.h>

#define BATCH 65536
#define IN_DIM 128
#define INT_NODES 255
#define LEAF 256
#define OUT_DIM 8
#define ROWS_PB 64
#define NBLK (BATCH / ROWS_PB)   // 1024 blocks; LDS 37KB + VGPR<=128 -> 4 blocks/CU
#define AMB_TH 5e-4f

typedef float  f4v __attribute__((ext_vector_type(4)));
typedef short  s8v __attribute__((ext_vector_type(8)));

__device__ __forceinline__ unsigned short bfhi(float f) {
    unsigned u = __builtin_bit_cast(unsigned, f);
    unsigned r = (u + 0x7FFFu + ((u >> 16) & 1u)) >> 16;   // RNE
    return (unsigned short)r;
}
__device__ __forceinline__ float bf2f(unsigned short h) {
    unsigned u = ((unsigned)h) << 16;
    return __builtin_bit_cast(float, u);
}

// Fused prepass: blocks [0,64) = LDS-tiled transpose Wor[o*128+i][l] -> Wor_t[l][o*128+i];
// blocks [64,192) = Wp -> MFMA B-fragments, bf16 hi/lo split, node 255 zero-pad.
__global__ __launch_bounds__(256) void prep(const float* __restrict__ Wor,
                                            float* __restrict__ Wor_t,
                                            const float* __restrict__ Wp,
                                            unsigned short* __restrict__ Bh,
                                            unsigned short* __restrict__ Bl) {
    if (blockIdx.x < 64) {
        __shared__ float t[64][65];
        const int rt = blockIdx.x >> 2, ct = blockIdx.x & 3;  // 16 x 4 tiles of 64x64
        const int r0 = rt * 64, c0 = ct * 64;
        const int tx = threadIdx.x & 63, ty = threadIdx.x >> 6;
#pragma unroll
        for (int p = 0; p < 16; ++p) {
            int r = ty + p * 4;
            t[r][tx] = Wor[(size_t)(r0 + r) * 256 + c0 + tx];     // coalesced
        }
        __syncthreads();
#pragma unroll
        for (int p = 0; p < 16; ++p) {
            int r = ty + p * 4;
            Wor_t[(size_t)(c0 + r) * 1024 + r0 + tx] = t[tx][r];  // coalesced
        }
    } else {
        // B-frag (16x16x32): B[k = ks*32+(lane>>4)*8+j][n = ntg*16+(lane&15)],
        // slot = ((ks*16+ntg)*64+lane)*8+j.
        int slot = (blockIdx.x - 64) * 256 + threadIdx.x;   // 32768
        int j    = slot & 7;
        int lane = (slot >> 3) & 63;
        int ntg  = (slot >> 9) & 15;
        int ks   = slot >> 13;
        int n = ntg * 16 + (lane & 15);
        int k = ks * 32 + (lane >> 4) * 8 + j;
        float v = (n < INT_NODES) ? Wp[n * IN_DIM + k] : 0.f;
        unsigned short h = bfhi(v);
        Bh[slot] = h;
        Bl[slot] = bfhi(v - bf2f(h));
    }
}

// NOTE: plain __launch_bounds__(256). R6's (256,4) made the compiler clamp to
// 64 VGPRs -> massive scratch spills (WRITE_SIZE 4->93 MB). Natural allocation
// is ~112 VGPRs (R5) which still permits 4 waves/SIMD (112*4 <= 512).
__global__ __launch_bounds__(256) void dgt_main(
    const float* __restrict__ x, const float* __restrict__ Wp,
    const float* __restrict__ bp, const unsigned short* __restrict__ Bhg,
    const unsigned short* __restrict__ Blg, const float* __restrict__ Wor_t,
    const float* __restrict__ bor, const float* __restrict__ stds,
    float* __restrict__ out, float* __restrict__ stdo) {

    // ~37 KB LDS -> 4 blocks/CU.
    __shared__ union {
        float ps[64 * 68];          // row-partials of sum|z+bp|: [m][wave*16+c]
        float hb[2 * 8 * 4 * 64];   // heads partials (phases 6-7; ps is dead)
    } u;
    __shared__ unsigned char sgn[256 * 72];  // 2-bit sign/ambig per (node,row)
    __shared__ float bpl[256];
    __shared__ int   leafbuf[64];
    __shared__ float psbuf[64];

    const int tid  = threadIdx.x;
    const int wave = tid >> 6;
    const int lane = tid & 63;
    const int rowbase = blockIdx.x * ROWS_PB;

    bpl[tid] = (tid < INT_NODES) ? bp[tid] : 0.f;

    // ---- phase 1+2: A-frags straight from global x (in-register, no LDS),
    //      3-product split-bf16 MFMA: z = xh*wh + xh*wl + xl*wh (fp32 acc). ----
    f4v acc[4][4];
#pragma unroll
    for (int mt = 0; mt < 4; ++mt)
#pragma unroll
        for (int nt = 0; nt < 4; ++nt) acc[mt][nt] = (f4v){0.f, 0.f, 0.f, 0.f};

    const s8v* Bh8 = (const s8v*)Bhg;
    const s8v* Bl8 = (const s8v*)Blg;
    const float* xbase = x + (size_t)rowbase * IN_DIM;
    const int arow = lane & 15, akq = lane >> 4;

#pragma unroll
    for (int ks = 0; ks < 4; ++ks) {
        s8v ah[4], al[4];
#pragma unroll
        for (int mt = 0; mt < 4; ++mt) {
            const float* p = xbase + (size_t)(mt * 16 + arow) * IN_DIM + ks * 32 + akq * 8;
            float4 v0 = *reinterpret_cast<const float4*>(p);
            float4 v1 = *reinterpret_cast<const float4*>(p + 4);
            float f[8] = {v0.x, v0.y, v0.z, v0.w, v1.x, v1.y, v1.z, v1.w};
            s8v hi, lo;
#pragma unroll
            for (int j = 0; j < 8; ++j) {
                unsigned short h = bfhi(f[j]);
                hi[j] = (short)h;
                lo[j] = (short)bfhi(f[j] - bf2f(h));
            }
            ah[mt] = hi; al[mt] = lo;
        }
#pragma unroll
        for (int nt = 0; nt < 4; ++nt) {
            int idx = (ks * 16 + (wave * 4 + nt)) * 64 + lane;   // coalesced, L2-hot
            s8v bh = Bh8[idx];
            s8v bl = Bl8[idx];
#pragma unroll
            for (int mt = 0; mt < 4; ++mt) {
                acc[mt][nt] = __builtin_amdgcn_mfma_f32_16x16x32_bf16(ah[mt], bh, acc[mt][nt], 0, 0, 0);
                acc[mt][nt] = __builtin_amdgcn_mfma_f32_16x16x32_bf16(ah[mt], bl, acc[mt][nt], 0, 0, 0);
                acc[mt][nt] = __builtin_amdgcn_mfma_f32_16x16x32_bf16(al[mt], bh, acc[mt][nt], 0, 0, 0);
            }
        }
    }
    __syncthreads();   // covers bpl write -> read

    // ---- phase 3: compress acc -> 2-bit sign/ambig bytes + row-partials of
    //      sum|z+bp| (z never materialized in LDS). ----
    // C/D layout: col n = wave*64 + nt*16 + (lane&15), row m = mt*16 + (lane>>4)*4 + reg.
    {
        const int c = lane & 15, g = lane >> 4;
        float pp[4][4];
#pragma unroll
        for (int mt = 0; mt < 4; ++mt)
#pragma unroll
            for (int r = 0; r < 4; ++r) pp[mt][r] = 0.f;

#pragma unroll
        for (int nt = 0; nt < 4; ++nt) {
            const int n = wave * 64 + nt * 16 + c;
            const float bpv = bpl[n];
#pragma unroll
            for (int mt = 0; mt < 4; ++mt) {
                unsigned pk = 0;
#pragma unroll
                for (int r = 0; r < 4; ++r) {
                    float v = acc[mt][nt][r] + bpv;
                    float av = fabsf(v);
                    pp[mt][r] += av;
                    unsigned b = (v < 0.f ? 1u : 0u) | (av < AMB_TH ? 2u : 0u);
                    pk |= b << (8 * r);
                }
                *reinterpret_cast<unsigned*>(&sgn[n * 72 + mt * 16 + g * 4]) = pk;
            }
        }
#pragma unroll
        for (int mt = 0; mt < 4; ++mt)
#pragma unroll
            for (int r = 0; r < 4; ++r)
                u.ps[(mt * 16 + g * 4 + r) * 68 + wave * 16 + c] = pp[mt][r];
    }
    __syncthreads();

    // ---- phase 5: traversal + closed-form p* (wave 0; 8 byte-lookups) ----
    if (wave == 0) {
        const int r = lane;
        float s = 0.f;
#pragma unroll
        for (int j = 0; j < 64; j += 4) {
            float4 v = *reinterpret_cast<const float4*>(&u.ps[r * 68 + j]);
            s += (v.x + v.y) + (v.z + v.w);
        }
        int node = 0;
#pragma unroll
        for (int d = 0; d < 8; ++d) {
            unsigned b = sgn[node * 72 + r];
            int neg;
            if (b & 2u) {          // rare: exact sign via fp64 from global
                double zd = (double)bpl[node];
                const float* wr = Wp + node * IN_DIM;
                const float* xrow = x + (size_t)(rowbase + r) * IN_DIM;
                for (int k = 0; k < IN_DIM; ++k)
                    zd = fma((double)wr[k], (double)xrow[k], zd);
                neg = (zd < 0.0) ? 1 : 0;
            } else {
                neg = (int)(b & 1u);
            }
            node = 2 * node + 1 + neg;
        }
        const float fac = s * (1.0f / (float)INT_NODES);
        // p* of argmax leaf: sum_l exp(and_z_l - 8 fac) = (1 + e^{-2 fac})^8.
        const float e = expf(-2.0f * fac);
        const float q = 1.0f + e;
        const float q2 = q * q, q4 = q2 * q2, q8 = q4 * q4;
        leafbuf[r] = node - INT_NODES;
        psbuf[r] = 1.0f / q8;
    }
    __syncthreads();

    // ---- phase 6: fp32 heads, K-split (identical numerics to R4/R5) ----
    {
        const int r = lane, sg = wave;
        const float* xp = x + (size_t)(rowbase + r) * IN_DIM + sg * 32;
        float xr[32];
#pragma unroll
        for (int i = 0; i < 32; i += 4) {
            float4 v = *reinterpret_cast<const float4*>(xp + i);
            xr[i] = v.x; xr[i + 1] = v.y; xr[i + 2] = v.z; xr[i + 3] = v.w;
        }
        const int leaf = leafbuf[r];
        const float* wl = Wor_t + (size_t)leaf * (OUT_DIM * IN_DIM) + sg * 32;
        const float* bb = bor + sg * 32;
#pragma unroll
        for (int o = 0; o < OUT_DIM; ++o) {
            const float* wo = wl + o * IN_DIM;
            const float* bo = bb + o * IN_DIM;
            float s0 = 0.f, s1 = 0.f, s2 = 0.f, s3 = 0.f;
            float b0 = 0.f, b1 = 0.f, b2 = 0.f, b3 = 0.f;
#pragma unroll
            for (int c2 = 0; c2 < 32; c2 += 4) {
                float4 wv = *reinterpret_cast<const float4*>(wo + c2);
                s0 = fmaf(wv.x, xr[c2 + 0], s0);
                s1 = fmaf(wv.y, xr[c2 + 1], s1);
                s2 = fmaf(wv.z, xr[c2 + 2], s2);
                s3 = fmaf(wv.w, xr[c2 + 3], s3);
                b0 = fmaf(bo[c2 + 0], xr[c2 + 0], b0);
                b1 = fmaf(bo[c2 + 1], xr[c2 + 1], b1);
                b2 = fmaf(bo[c2 + 2], xr[c2 + 2], b2);
                b3 = fmaf(bo[c2 + 3], xr[c2 + 3], b3);
            }
            u.hb[((0 * 8 + o) * 4 + sg) * 64 + r] = (s0 + s1) + (s2 + s3);
            u.hb[((1 * 8 + o) * 4 + sg) * 64 + r] = (b0 + b1) + (b2 + b3);
        }
    }
    __syncthreads();

    // ---- phase 7: final reduce + stores (2 outputs/thread) ----
    {
        const int r = tid & 63;
        const int og = tid >> 6;
        const float ps = psbuf[r];
        const int lf = leafbuf[r];
#pragma unroll
        for (int uu = 0; uu < 2; ++uu) {
            const int o = og * 2 + uu;
            float s = u.hb[((0 * 8 + o) * 4 + 0) * 64 + r] + u.hb[((0 * 8 + o) * 4 + 1) * 64 + r]
                    + u.hb[((0 * 8 + o) * 4 + 2) * 64 + r] + u.hb[((0 * 8 + o) * 4 + 3) * 64 + r];
            float b = u.hb[((1 * 8 + o) * 4 + 0) * 64 + r] + u.hb[((1 * 8 + o) * 4 + 1) * 64 + r]
                    + u.hb[((1 * 8 + o) * 4 + 2) * 64 + r] + u.hb[((1 * 8 + o) * 4 + 3) * 64 + r];
            out[(size_t)(rowbase + r) * OUT_DIM + o] = ps * s + b;
            float sd = ps * stds[lf * OUT_DIM + o];
            stdo[(size_t)(rowbase + r) * OUT_DIM + o] = fminf(fmaxf(sd, -20.0f), 2.0f);
        }
    }
}

extern "C" void kernel_launch(void* const* d_in, const int* in_sizes, int n_in,
                              void* d_out, int out_size, void* d_ws, size_t ws_size,
                              hipStream_t stream) {
    const float* x    = (const float*)d_in[0];
    const float* Wp   = (const float*)d_in[1];
    const float* bp   = (const float*)d_in[2];
    // d_in[3] = Wand -- folded into the traversal, unused.
    const float* Wor  = (const float*)d_in[4];
    const float* bor  = (const float*)d_in[5];
    const float* stds = (const float*)d_in[6];
    float* out = (float*)d_out;

    float* wor_t = (float*)d_ws;                                              // 1 MB
    unsigned short* Bh = (unsigned short*)((char*)d_ws + (1 << 20));          // 64 KB
    unsigned short* Bl = (unsigned short*)((char*)d_ws + (1 << 20) + (64 << 10)); // 64 KB

    prep<<<192, 256, 0, stream>>>(Wor, wor_t, Wp, Bh, Bl);
    dgt_main<<<NBLK, 256, 0, stream>>>(x, Wp, bp, Bh, Bl, wor_t, bor, stds,
                                       out, out + (size_t)BATCH * OUT_DIM);
}